// Round 4
// baseline (257.748 us; speedup 1.0000x reference)
//
#include <hip/hip_runtime.h>

// IRFDeconv3D: out[b,p,t] = sum_{tau<=t} data[b,p,tau] * knorm[b,t-tau]
// == per-batch GEMM A[16384x256] @ Toeplitz(knorm)[256x256], keep n<256.
//
// v8: dynamic-occupancy attack. v5/v6/v7 all pinned at ~35% occupancy /
// 86us despite static limits allowing 2-3x more residency -> the cap is
// dynamic: short-lived blocks (dispatch/prologue overhead) + in-order
// vmcnt coupling that made every iteration wait on the PREVIOUS
// iteration's stores. Changes:
//  - 1024 persistent-ish blocks x 2 tiles: fully co-resident (4 blocks/CU
//    at <=128 VGPR, 16 KiB LDS), single dispatch wave, B staged ONCE.
//  - Per tile: all 16 A loads upfront (one latency exposure), cvt to
//    bf16, then compute. Tile-1 loads issue BEFORE tile-0 stores, so
//    vmcnt waits (in-order) drain loads only, never stores.
//  - Zero barriers in steady state (one __syncthreads after B staging).
//  - B re-laid-out [d][lane]: wave's ds_read_b128 is contiguous 1 KiB ->
//    bank-conflict-free (v7 showed 2.88M conflict cycles on the old
//    [d][row][chunk] layout).

typedef __attribute__((ext_vector_type(8))) short short8;
typedef __attribute__((ext_vector_type(4))) float floatx4;

#define T_BINS 256
#define PIX_PER_B (128 * 128)

typedef __attribute__((address_space(3))) void lds_void;
typedef __attribute__((address_space(1))) const void gbl_void;

__device__ __forceinline__ void gload_lds16(const void* g, void* l) {
    __builtin_amdgcn_global_load_lds((gbl_void*)g, (lds_void*)l, 16, 0, 0);
}

__device__ inline unsigned short f2bf(float f) {
    unsigned int u = __float_as_uint(f);
    u += 0x7fffu + ((u >> 16) & 1u);   // round-to-nearest-even
    return (unsigned short)(u >> 16);
}

// W[b][e'] with e' = d*512 + lq*128 + np*8 + k8 (shorts).
// value = knorm[16*d + np - kl] (kl = lq*8 + k8) if idx >= 0 else 0.
// Lane l of a wave reads frag d at shorts [d*512 + l*8, +8) -> contiguous.
__global__ __launch_bounds__(256) void build_W(const float* __restrict__ irf,
                                               unsigned short* __restrict__ W) {
    __shared__ float red[256];
    __shared__ float knorm[256];
    const int b = blockIdx.x;
    const int t = threadIdx.x;
    float v = irf[b * T_BINS + t];
    red[t] = v;
    __syncthreads();
    for (int s = 128; s > 0; s >>= 1) {
        if (t < s) red[t] = fmaxf(red[t], red[t + s]);
        __syncthreads();
    }
    knorm[t] = v / red[0];
    __syncthreads();
    unsigned short* Wb = W + b * 8192;
#pragma unroll
    for (int i = 0; i < 32; i++) {
        int e = i * 256 + t;            // coalesced
        int d  = e >> 9;
        int lq = (e >> 7) & 3;
        int np = (e >> 3) & 15;
        int k8 = e & 7;
        int kl = lq * 8 + k8;
        int idx = 16 * d + np - kl;
        Wb[e] = (idx >= 0) ? f2bf(knorm[idx]) : (unsigned short)0;
    }
}

__device__ inline short8 cvt_a(float4 lo, float4 hi) {
    short8 a;
    a[0] = (short)f2bf(lo.x); a[1] = (short)f2bf(lo.y);
    a[2] = (short)f2bf(lo.z); a[3] = (short)f2bf(lo.w);
    a[4] = (short)f2bf(hi.x); a[5] = (short)f2bf(hi.y);
    a[6] = (short)f2bf(hi.z); a[7] = (short)f2bf(hi.w);
    return a;
}

__global__ __launch_bounds__(256, 4) void conv_gemm(const float* __restrict__ data,
                                                    const unsigned short* __restrict__ W,
                                                    float* __restrict__ out) {
    __shared__ alignas(16) unsigned short Bs[8192];   // 16 KiB

    const int b = blockIdx.x >> 7;        // 8 batches x 128 blocks
    const int bm = blockIdx.x & 127;      // tiles bm and bm+128
    const int t = threadIdx.x;
    const int w = t >> 6;
    const int l = t & 63;
    const int lq = l >> 4;
    const int lm = l & 15;

    // ---- stage B table once (4 DMA instrs, linear) ----
    const unsigned short* Wb = W + b * 8192;
#pragma unroll
    for (int i = 0; i < 4; i++)
        gload_lds16(Wb + (i * 256 + t) * 8,
                    (unsigned char*)Bs + i * 4096 + w * 1024);

    const int mt0 = bm, mt1 = bm + 128;
    const float* A0 = data + ((size_t)b * PIX_PER_B + mt0 * 64 + w * 16 + lm) * T_BINS + lq * 8;
    const float* A1 = data + ((size_t)b * PIX_PER_B + mt1 * 64 + w * 16 + lm) * T_BINS + lq * 8;
    float* O0 = out + ((size_t)b * PIX_PER_B + mt0 * 64 + w * 16 + lm) * T_BINS;
    float* O1 = out + ((size_t)b * PIX_PER_B + mt1 * 64 + w * 16 + lm) * T_BINS;
    const unsigned short* BsL = Bs + l * 8;   // + d*512 per frag (contiguous/wave)

    float4 raw[8][2];
    short8 af[8];

    // ---- LOAD(T0): all 16 loads in flight, one latency exposure ----
#pragma unroll
    for (int kk = 0; kk < 8; kk++) {
        raw[kk][0] = *(const float4*)(A0 + kk * 32);
        raw[kk][1] = *(const float4*)(A0 + kk * 32 + 4);
    }
    __builtin_amdgcn_sched_barrier(0);

    // ---- CVT(T0): compiler inserts counted vmcnt per slab ----
#pragma unroll
    for (int kk = 0; kk < 8; kk++) af[kk] = cvt_a(raw[kk][0], raw[kk][1]);

    __syncthreads();                      // Bs ready (drains B DMA; raws consumed)

    // ---- LOAD(T1) BEFORE any store: loads stay oldest in vmcnt queue ----
#pragma unroll
    for (int kk = 0; kk < 8; kk++) {
        raw[kk][0] = *(const float4*)(A1 + kk * 32);
        raw[kk][1] = *(const float4*)(A1 + kk * 32 + 4);
    }
    __builtin_amdgcn_sched_barrier(0);

    // ---- COMPUTE+STORE(T0): ds_read + MFMA only; stores fire-and-forget ----
#pragma unroll
    for (int j = 0; j < 16; j++) {
        floatx4 acc = (floatx4){0.f, 0.f, 0.f, 0.f};
#pragma unroll
        for (int k2 = 0; k2 <= (j >> 1); k2++) {
            short8 bf = *(const short8*)(BsL + (j - 2 * k2) * 512);
            acc = __builtin_amdgcn_mfma_f32_16x16x32_bf16(bf, af[k2], acc, 0, 0, 0);
        }
        *reinterpret_cast<floatx4*>(O0 + 16 * j + 4 * lq) = acc;
    }
    __builtin_amdgcn_sched_barrier(0);

    // ---- CVT(T1): waits drain T1 loads (oldest); T0 stores unaffected ----
#pragma unroll
    for (int kk = 0; kk < 8; kk++) af[kk] = cvt_a(raw[kk][0], raw[kk][1]);

    // ---- COMPUTE+STORE(T1) ----
#pragma unroll
    for (int j = 0; j < 16; j++) {
        floatx4 acc = (floatx4){0.f, 0.f, 0.f, 0.f};
#pragma unroll
        for (int k2 = 0; k2 <= (j >> 1); k2++) {
            short8 bf = *(const short8*)(BsL + (j - 2 * k2) * 512);
            acc = __builtin_amdgcn_mfma_f32_16x16x32_bf16(bf, af[k2], acc, 0, 0, 0);
        }
        *reinterpret_cast<floatx4*>(O1 + 16 * j + 4 * lq) = acc;
    }
}

extern "C" void kernel_launch(void* const* d_in, const int* in_sizes, int n_in,
                              void* d_out, int out_size, void* d_ws, size_t ws_size,
                              hipStream_t stream) {
    const float* data = (const float*)d_in[0];   // [8,128,128,256,1] fp32
    const float* irf  = (const float*)d_in[1];   // [8,1,1,256,1] fp32
    float* outp = (float*)d_out;                 // [8,128,128,256,1] fp32
    unsigned short* W = (unsigned short*)d_ws;   // 8*8192 bf16 = 128 KiB

    build_W<<<8, 256, 0, stream>>>(irf, W);
    conv_gemm<<<1024, 256, 0, stream>>>(data, W, outp);
}

// Round 5
// 252.106 us; speedup vs baseline: 1.0224x; 1.0224x over previous
//
#include <hip/hip_runtime.h>

// IRFDeconv3D: out[b,p,t] = sum_{tau<=t} data[b,p,tau] * knorm[b,t-tau]
// == per-batch GEMM A[16384x256] @ Toeplitz(knorm)[256x256], keep n<256.
//
// v9: L3-thrash attack. FETCH_SIZE 66MB vs 134MB input shows half the
// reads already hit Infinity Cache, but input+output = 268MB > 256MB L3,
// so the (never-read) output stream evicts the input every iteration.
//  - NON-TEMPORAL stores (nt bit, no-allocate): output bypasses L2/L3
//    allocation -> input becomes L3-resident -> read latency drops.
//  - Revert v8's 2-tile (it caused +25% write amplification: j-pair
//    half-line stores drifted apart). Single tile, j-outer paired stores
//    (v5-v7 measured WRITE_SIZE == exact ideal with this order).
//  - Keep v8's conflict-free B layout [d][lane] (0 bank conflicts).
//  - All 16 A loads upfront, ISSUED BEFORE B-DMA so cvt waits at
//    vmcnt(4), and one latency exposure per wave.

typedef __attribute__((ext_vector_type(8))) short short8;
typedef __attribute__((ext_vector_type(4))) float floatx4;

#define T_BINS 256
#define PIX_PER_B (128 * 128)

typedef __attribute__((address_space(3))) void lds_void;
typedef __attribute__((address_space(1))) const void gbl_void;

__device__ __forceinline__ void gload_lds16(const void* g, void* l) {
    __builtin_amdgcn_global_load_lds((gbl_void*)g, (lds_void*)l, 16, 0, 0);
}

__device__ inline unsigned short f2bf(float f) {
    unsigned int u = __float_as_uint(f);
    u += 0x7fffu + ((u >> 16) & 1u);   // round-to-nearest-even
    return (unsigned short)(u >> 16);
}

// W[b][e'] with e' = d*512 + lq*128 + np*8 + k8 (shorts).
// value = knorm[16*d + np - kl] (kl = lq*8 + k8) if idx >= 0 else 0.
// Lane l of a wave reads frag d at shorts [d*512 + l*8, +8) -> contiguous.
__global__ __launch_bounds__(256) void build_W(const float* __restrict__ irf,
                                               unsigned short* __restrict__ W) {
    __shared__ float red[256];
    __shared__ float knorm[256];
    const int b = blockIdx.x;
    const int t = threadIdx.x;
    float v = irf[b * T_BINS + t];
    red[t] = v;
    __syncthreads();
    for (int s = 128; s > 0; s >>= 1) {
        if (t < s) red[t] = fmaxf(red[t], red[t + s]);
        __syncthreads();
    }
    knorm[t] = v / red[0];
    __syncthreads();
    unsigned short* Wb = W + b * 8192;
#pragma unroll
    for (int i = 0; i < 32; i++) {
        int e = i * 256 + t;            // coalesced
        int d  = e >> 9;
        int lq = (e >> 7) & 3;
        int np = (e >> 3) & 15;
        int k8 = e & 7;
        int kl = lq * 8 + k8;
        int idx = 16 * d + np - kl;
        Wb[e] = (idx >= 0) ? f2bf(knorm[idx]) : (unsigned short)0;
    }
}

__device__ inline short8 cvt_a(float4 lo, float4 hi) {
    short8 a;
    a[0] = (short)f2bf(lo.x); a[1] = (short)f2bf(lo.y);
    a[2] = (short)f2bf(lo.z); a[3] = (short)f2bf(lo.w);
    a[4] = (short)f2bf(hi.x); a[5] = (short)f2bf(hi.y);
    a[6] = (short)f2bf(hi.z); a[7] = (short)f2bf(hi.w);
    return a;
}

__global__ __launch_bounds__(256, 4) void conv_gemm(const float* __restrict__ data,
                                                    const unsigned short* __restrict__ W,
                                                    float* __restrict__ out) {
    __shared__ alignas(16) unsigned short Bs[8192];   // 16 KiB

    const int b = blockIdx.x >> 8;        // 256 m-tiles per batch
    const int mt = blockIdx.x & 255;
    const int t = threadIdx.x;
    const int w = t >> 6;
    const int l = t & 63;
    const int lq = l >> 4;
    const int lm = l & 15;

    const float* A0 = data + ((size_t)b * PIX_PER_B + mt * 64 + w * 16 + lm) * T_BINS + lq * 8;
    float* O0 = out + ((size_t)b * PIX_PER_B + mt * 64 + w * 16 + lm) * T_BINS;
    const unsigned short* BsL = Bs + l * 8;   // + d*512 per frag (contiguous/wave)

    float4 raw[8][2];

    // ---- A loads FIRST (oldest in vmcnt queue): one latency exposure ----
#pragma unroll
    for (int kk = 0; kk < 8; kk++) {
        raw[kk][0] = *(const float4*)(A0 + kk * 32);
        raw[kk][1] = *(const float4*)(A0 + kk * 32 + 4);
    }
    __builtin_amdgcn_sched_barrier(0);

    // ---- B table DMA (4 instrs, linear; younger than A loads) ----
    const unsigned short* Wb = W + b * 8192;
#pragma unroll
    for (int i = 0; i < 4; i++)
        gload_lds16(Wb + (i * 256 + t) * 8,
                    (unsigned char*)Bs + i * 4096 + w * 1024);
    __builtin_amdgcn_sched_barrier(0);

    // ---- CVT: consumes A loads via counted vmcnt (>=4, B-DMA younger) ----
    short8 af[8];
#pragma unroll
    for (int kk = 0; kk < 8; kk++) af[kk] = cvt_a(raw[kk][0], raw[kk][1]);

    __syncthreads();                      // Bs ready

    // ---- COMPUTE + NT-STORE: j-pairs adjacent so 128B lines complete ----
#pragma unroll
    for (int j = 0; j < 16; j++) {
        floatx4 acc = (floatx4){0.f, 0.f, 0.f, 0.f};
#pragma unroll
        for (int k2 = 0; k2 <= (j >> 1); k2++) {
            short8 bf = *(const short8*)(BsL + (j - 2 * k2) * 512);
            acc = __builtin_amdgcn_mfma_f32_16x16x32_bf16(bf, af[k2], acc, 0, 0, 0);
        }
        // non-temporal: no L2/L3 allocate -> input stays L3-resident
        __builtin_nontemporal_store(acc, (floatx4*)(O0 + 16 * j + 4 * lq));
        __builtin_amdgcn_sched_barrier(0);   // keep j-pair stores adjacent
    }
}

extern "C" void kernel_launch(void* const* d_in, const int* in_sizes, int n_in,
                              void* d_out, int out_size, void* d_ws, size_t ws_size,
                              hipStream_t stream) {
    const float* data = (const float*)d_in[0];   // [8,128,128,256,1] fp32
    const float* irf  = (const float*)d_in[1];   // [8,1,1,256,1] fp32
    float* outp = (float*)d_out;                 // [8,128,128,256,1] fp32
    unsigned short* W = (unsigned short*)d_ws;   // 8*8192 bf16 = 128 KiB

    build_W<<<8, 256, 0, stream>>>(irf, W);
    conv_gemm<<<2048, 256, 0, stream>>>(data, W, outp);
}